// Round 16
// baseline (917.117 us; speedup 1.0000x reference)
//
#include <hip/hip_runtime.h>

// RNN: h_t = tanh(x[b,t]*W_ih + b_ih + b_hh + h_{t-1} @ W_hh^T), out = h_T @ W_out^T + b_out
// B=256 T=2048 H=256 P=24, fp32 in/out. One WG/batch (256 WGs = 256 CUs), 1024 thr, 16 waves.
//
// Round-25: MFMA at 4 WAVES/SIMD + VALU diet. R15 (2 waves/SIMD, 868us)
// counter decomposition: MFMA floor 155 cyc/SIMD, VALUBusy 305 cyc (16
// acc-init moves + ~32 af moves + 20 tail insts + addr, x2 waves), ~550
// stall partially hidden. All three attack lines:
//  - 16 waves x 16 rows: 4 streams/SIMD hide MFMA dep + DS broadcast +
//    tail latency. Per-SIMD MFMA unchanged (4x8=32).
//  - acc zero-init DELETED: first MFMA of each chain takes a persistent
//    zero C operand (MFMA C-src != D-dst, no copy). af used once each ->
//    no double-use moves. Tail = 1 tanh + 1 ds_write_b16 on lanes 0-15.
//  - VGPR ~97 < 128 budget at 4 waves/EU. If wf gets AGPR-stashed it is
//    HARMLESS: MFMA reads A/B from AGPRs natively (R13's vector-op move
//    tax does not apply). Spill -> FETCH_SIZE jump (diagnostic).
// Known risk: DS broadcast reads double (128 b128/CU/step ~512 cyc DS
// pipe); DS runs parallel to MFMA/VALU -> worst case DS-bound ~600cyc step,
// still a win. A/B layout verified (R14/R15, absmax 3.9e-3): A = h
// broadcast, lane l reads h[32kb+8*(l>>4)+j] (16-lane same-addr groups);
// B = W rows in regs, same k-formula -> HW k-permutation cancels; C/D col
// = lane&15, rows replicated -> acc.x = row sum. 2-chain split-K combine
// y = a0.x + a1.x (same reassociation class as R15).
// Locked-in: fp16 h storage; lgkm-only barrier; x block-prefetch; fp32
// tanh (exp2/rcp); fp32 head on tid<24.

#define BB 256
#define TT 2048
#define HH 256
#define PP 24

typedef _Float16 half_t;
typedef _Float16 h8v __attribute__((ext_vector_type(8)));
typedef float    f4v __attribute__((ext_vector_type(4)));

__device__ __forceinline__ f4v mfma16(h8v a, h8v b, f4v c) {
    return __builtin_amdgcn_mfma_f32_16x16x32_f16(a, b, c, 0, 0, 0);
}

// LDS-only barrier: orders the ds_writes without draining vmcnt (x prefetch
// stays in flight; compiler waits vmcnt at first use).
__device__ __forceinline__ void lds_barrier() {
    asm volatile("s_waitcnt lgkmcnt(0)\n\ts_barrier" ::: "memory");
}

__global__ __launch_bounds__(1024)
void rnn_persist(const float* __restrict__ x,
                 const float* __restrict__ W_ih,
                 const float* __restrict__ W_hh,
                 const float* __restrict__ b_ih,
                 const float* __restrict__ b_hh,
                 const float* __restrict__ W_out,
                 const float* __restrict__ b_out,
                 float* __restrict__ out)
{
    __shared__ __align__(16) half_t hbuf[2][HH];   // 2 x 512 B

    const int tid  = threadIdx.x;
    const int b    = blockIdx.x;
    const int w    = tid >> 6;        // wave 0..15 -> owns y[16w .. 16w+15]
    const int l    = tid & 63;
    const int ln   = l & 15;          // col within 16-block (C/D col = lane&15)
    const int kg   = l >> 4;          // k-group 0..3 (8 k-slots each)

    hbuf[0][tid & 255] = (half_t)0.f; // h_0 = 0 (4-dup same-addr, same value)

    // B-operand weights: wf[kb] = W[16w+ln][32kb+8kg+j], j=0..7. 32 VGPRs
    // (AGPR placement harmless: MFMA reads AGPR operands natively).
    h8v wf[8];
    #pragma unroll
    for (int kb = 0; kb < 8; ++kb) {
        const float* p = W_hh + (size_t)(16 * w + ln) * HH + 32 * kb + 8 * kg;
        const float4 qa = *(const float4*)p;
        const float4 qb = *(const float4*)(p + 4);
        wf[kb] = (h8v){(half_t)qa.x, (half_t)qa.y, (half_t)qa.z, (half_t)qa.w,
                       (half_t)qb.x, (half_t)qb.y, (half_t)qb.z, (half_t)qb.w};
    }

    // Row this lane finalizes (lanes 0-15 only): o = 16w + ln.
    const int   o   = 16 * w + ln;
    const float wih = W_ih[o];
    const float cb  = b_ih[o] + b_hh[o];
    const bool  writer = (l < 16);

    __syncthreads();

    const float* xb = x + b * TT;

    auto step = [&](const half_t* __restrict__ cur, half_t* __restrict__ nxt,
                    float xt) __attribute__((always_inline)) {
        // A fragments: 8 broadcast ds_read_b128 (base + kg*16 + kb*64 bytes;
        // 16-lane same-addr groups, conflict-free). Issued back-to-back.
        const h8v* hp = (const h8v*)(cur + 8 * kg);
        const h8v af0 = hp[0],  af1 = hp[4],  af2 = hp[8],  af3 = hp[12];
        const h8v af4 = hp[16], af5 = hp[20], af6 = hp[24], af7 = hp[28];

        // 2 interleaved 4-deep chains; first MFMA consumes a zero C operand
        // (no acc-init moves). Each af feeds exactly one MFMA (no reuse).
        const f4v zf = {0.f, 0.f, 0.f, 0.f};
        f4v a0 = mfma16(af0, wf[0], zf);
        f4v a1 = mfma16(af4, wf[4], zf);
        a0 = mfma16(af1, wf[1], a0);
        a1 = mfma16(af5, wf[5], a1);
        a0 = mfma16(af2, wf[2], a0);
        a1 = mfma16(af6, wf[6], a1);
        a0 = mfma16(af3, wf[3], a0);
        a1 = mfma16(af7, wf[7], a1);

        // Tail (writer lanes): rows replicated -> acc.x = row sum partials.
        if (writer) {
            const float y  = a0.x + a1.x;
            const float u  = fmaf(xt, wih, cb) + y;
            const float p  = __builtin_amdgcn_exp2f(u * 2.8853900817779268f);
            const float th = fmaf(-2.f, __builtin_amdgcn_rcpf(p + 1.f), 1.f);
            nxt[o] = (half_t)th;   // one b16 write per row, no dup
        }
        lds_barrier();   // lgkm-only: x prefetch stays in flight
    };

    // x block-prefetch: block's two float4s fetched one 8-step block ahead.
    float4 xa = *(const float4*)(xb + 0);
    float4 xc = *(const float4*)(xb + 4);
    for (int t = 0; t < TT; t += 8) {
        const int tn = (t + 8 < TT) ? (t + 8) : t;   // clamped (last block refetch)
        const float4 xa_n = *(const float4*)(xb + tn);
        const float4 xc_n = *(const float4*)(xb + tn + 4);
        step(hbuf[0], hbuf[1], xa.x);
        step(hbuf[1], hbuf[0], xa.y);
        step(hbuf[0], hbuf[1], xa.z);
        step(hbuf[1], hbuf[0], xa.w);
        step(hbuf[0], hbuf[1], xc.x);
        step(hbuf[1], hbuf[0], xc.y);
        step(hbuf[0], hbuf[1], xc.z);
        step(hbuf[1], hbuf[0], xc.w);
        xa = xa_n;
        xc = xc_n;
    }

    // Head: h_T in hbuf[0] (TT % 8 == 0). out[b,p] = b_out[p] + W_out[p,:].h_T
    if (tid < PP) {
        const float* wo = W_out + tid * HH;
        float s0 = 0.f, s1 = 0.f, s2 = 0.f, s3 = 0.f;
        #pragma unroll
        for (int h = 0; h < HH; h += 4) {
            s0 = fmaf(wo[h + 0], (float)hbuf[0][h + 0], s0);
            s1 = fmaf(wo[h + 1], (float)hbuf[0][h + 1], s1);
            s2 = fmaf(wo[h + 2], (float)hbuf[0][h + 2], s2);
            s3 = fmaf(wo[h + 3], (float)hbuf[0][h + 3], s3);
        }
        out[b * PP + tid] = b_out[tid] + (s0 + s1) + (s2 + s3);
    }
}

extern "C" void kernel_launch(void* const* d_in, const int* in_sizes, int n_in,
                              void* d_out, int out_size, void* d_ws, size_t ws_size,
                              hipStream_t stream) {
    const float* x     = (const float*)d_in[0];
    const float* W_ih  = (const float*)d_in[1];
    const float* W_hh  = (const float*)d_in[2];
    const float* b_ih  = (const float*)d_in[3];
    const float* b_hh  = (const float*)d_in[4];
    const float* W_out = (const float*)d_in[5];
    const float* b_out = (const float*)d_in[6];
    float* out = (float*)d_out;

    rnn_persist<<<BB, 1024, 0, stream>>>(x, W_ih, W_hh, b_ih, b_hh, W_out, b_out, out);
}

// Round 17
// 844.216 us; speedup vs baseline: 1.0864x; 1.0864x over previous
//
#include <hip/hip_runtime.h>

// RNN: h_t = tanh(x[b,t]*W_ih + b_ih + b_hh + h_{t-1} @ W_hh^T), out = h_T @ W_out^T + b_out
// B=256 T=2048 H=256 P=24, fp32 in/out. One WG/batch (256 WGs = 256 CUs), 512 thr, 8 waves.
//
// Round-26: R15 + EXPOSURE TRIMS. R14/R15/R16 counters: MFMA busy is
// constant ~519-556 cyc/CU-step = ~16 cyc/MFMA = the 2075 TF ceiling
// (128 MFMA x 16384 FLOP / 3377 FLOP/cyc/CU = 620 cyc saturated floor ->
// 529us wall floor for the pure-MFMA structure; per-WG MFMA count is fixed
// at 128 = N/16 x K/32 regardless of wave/batch arrangement). R16's 4
// waves/SIMD regressed: DS broadcast reads doubled (128 b128/CU) + skew.
// R15 (8 waves, 64 reads, 2/SIMD) is the right shape: 1018 cyc =
// 519 busy + ~500 exposed. This round hides exposure, FP graph untouched:
//  1. rb0 chains complete first -> tail0 (~60cyc VALU/trans) overlaps
//     rb1's ~130cyc of matrix work (dep-graph enforced).
//  2. s_setprio(1) around the MFMA cluster (T5: favors the MFMA-issuing
//     wave over the tail-computing wave; 2 waves/SIMD are phase-diverse).
//  3. Zero-C first MFMA (R16's one good part): kills 16 acc-init movs.
//  4. u_pre = fmaf(xt,wih,cb) hoisted above the chains (y-independent).
// Identical FP ops & associations -> absmax exactly 0.00390625.
// A/B layout (R14/R15-verified): A = h broadcast, lane l reads
// h[32kb+8*(l>>4)+j] (one ds_read_b128/kb, 16-lane same-addr groups,
// conflict-free); B = W rows in regs, same k-formula -> HW k-permutation
// cancels; C/D col = lane&15, rows replicated -> acc.x = row sum.
// Locked-in: fp16 h storage; lgkm-only barrier (vmcnt stays in flight);
// x block-prefetch one 8-step block ahead; fp32 tanh (exp2/rcp); fp32 head.

#define BB 256
#define TT 2048
#define HH 256
#define PP 24

typedef _Float16 half_t;
typedef _Float16 h8v __attribute__((ext_vector_type(8)));
typedef float    f4v __attribute__((ext_vector_type(4)));

__device__ __forceinline__ f4v mfma16(h8v a, h8v b, f4v c) {
    return __builtin_amdgcn_mfma_f32_16x16x32_f16(a, b, c, 0, 0, 0);
}

// LDS-only barrier: orders the ds_writes without draining vmcnt (x prefetch
// stays in flight; compiler waits vmcnt at first use).
__device__ __forceinline__ void lds_barrier() {
    asm volatile("s_waitcnt lgkmcnt(0)\n\ts_barrier" ::: "memory");
}

__global__ __launch_bounds__(512, 2)
void rnn_persist(const float* __restrict__ x,
                 const float* __restrict__ W_ih,
                 const float* __restrict__ W_hh,
                 const float* __restrict__ b_ih,
                 const float* __restrict__ b_hh,
                 const float* __restrict__ W_out,
                 const float* __restrict__ b_out,
                 float* __restrict__ out)
{
    __shared__ __align__(16) half_t hbuf[2][HH];   // 2 x 512 B

    const int tid  = threadIdx.x;
    const int b    = blockIdx.x;
    const int w    = tid >> 6;        // wave 0..7 -> owns y[32w .. 32w+31]
    const int l    = tid & 63;
    const int ln   = l & 15;          // col within 16-block (C/D col = lane&15)
    const int kg   = l >> 4;          // k-group 0..3 (8 k-slots each)

    hbuf[0][tid & 255] = (half_t)0.f; // h_0 = 0 (2-dup same-addr, same value)

    // B-operand weights in regs: wf[rb][kb] = W[32w+16rb+ln][32kb+8kg+j],
    // j=0..7 (f16). 2*8*4 = 64 VGPRs.
    h8v wf[2][8];
    #pragma unroll
    for (int rb = 0; rb < 2; ++rb) {
        #pragma unroll
        for (int kb = 0; kb < 8; ++kb) {
            const float* p = W_hh + (size_t)(32 * w + 16 * rb + ln) * HH
                                   + 32 * kb + 8 * kg;
            const float4 qa = *(const float4*)p;
            const float4 qb = *(const float4*)(p + 4);
            wf[rb][kb] = (h8v){(half_t)qa.x, (half_t)qa.y, (half_t)qa.z,
                               (half_t)qa.w, (half_t)qb.x, (half_t)qb.y,
                               (half_t)qb.z, (half_t)qb.w};
        }
    }

    // Rows this lane finalizes (lanes 0-15 only): 32w + 16rb + ln.
    float wihv[2], cbv[2];
    #pragma unroll
    for (int rb = 0; rb < 2; ++rb) {
        const int o = 32 * w + 16 * rb + ln;
        wihv[rb] = W_ih[o];
        cbv[rb]  = b_ih[o] + b_hh[o];
    }
    const bool writer = (l < 16);

    __syncthreads();

    const float* xb = x + b * TT;
    const f4v zf = {0.f, 0.f, 0.f, 0.f};   // loop-invariant zero C operand

    auto step = [&](const half_t* __restrict__ cur, half_t* __restrict__ nxt,
                    float xt) __attribute__((always_inline)) {
        // A fragments: 8 broadcast ds_read_b128 (base + kg*16 + kb*64 bytes).
        const h8v* hp = (const h8v*)(cur + 8 * kg);
        h8v af[8];
        #pragma unroll
        for (int kb = 0; kb < 8; ++kb) af[kb] = hp[4 * kb];

        // Hoisted input projection (independent of the matvec).
        const float u0p = fmaf(xt, wihv[0], cbv[0]);
        const float u1p = fmaf(xt, wihv[1], cbv[1]);

        // rb0's two split-K chains finish first (tail0 then overlaps rb1's
        // matrix work); zero-C first MFMA (no acc-init movs).
        __builtin_amdgcn_s_setprio(1);
        f4v a00 = mfma16(af[0], wf[0][0], zf);
        f4v a01 = mfma16(af[4], wf[0][4], zf);
        a00 = mfma16(af[1], wf[0][1], a00);
        a01 = mfma16(af[5], wf[0][5], a01);
        a00 = mfma16(af[2], wf[0][2], a00);
        a01 = mfma16(af[6], wf[0][6], a01);
        a00 = mfma16(af[3], wf[0][3], a00);
        a01 = mfma16(af[7], wf[0][7], a01);
        f4v a10 = mfma16(af[0], wf[1][0], zf);
        f4v a11 = mfma16(af[4], wf[1][4], zf);
        a10 = mfma16(af[1], wf[1][1], a10);
        a11 = mfma16(af[5], wf[1][5], a11);
        a10 = mfma16(af[2], wf[1][2], a10);
        a11 = mfma16(af[6], wf[1][6], a11);
        a10 = mfma16(af[3], wf[1][3], a10);
        a11 = mfma16(af[7], wf[1][7], a11);
        __builtin_amdgcn_s_setprio(0);

        // Tails (writer lanes): rb0 first -- its accs are ready ~8 MFMA
        // issues before rb1's; the VALU/trans work hides under rb1.
        if (writer) {
            const float y0 = a00.x + a01.x;
            const float u0 = u0p + y0;
            const float p0 = __builtin_amdgcn_exp2f(u0 * 2.8853900817779268f);
            const float t0 = fmaf(-2.f, __builtin_amdgcn_rcpf(p0 + 1.f), 1.f);
            nxt[32 * w + ln] = (half_t)t0;            // row rb0, written early
            const float y1 = a10.x + a11.x;
            const float u1 = u1p + y1;
            const float p1 = __builtin_amdgcn_exp2f(u1 * 2.8853900817779268f);
            const float t1 = fmaf(-2.f, __builtin_amdgcn_rcpf(p1 + 1.f), 1.f);
            nxt[32 * w + 16 + ln] = (half_t)t1;       // row rb1
        }
        lds_barrier();   // lgkm-only: x prefetch stays in flight
    };

    // x block-prefetch: block's two float4s fetched one 8-step block ahead.
    float4 xa = *(const float4*)(xb + 0);
    float4 xc = *(const float4*)(xb + 4);
    for (int t = 0; t < TT; t += 8) {
        const int tn = (t + 8 < TT) ? (t + 8) : t;   // clamped (last block refetch)
        const float4 xa_n = *(const float4*)(xb + tn);
        const float4 xc_n = *(const float4*)(xb + tn + 4);
        step(hbuf[0], hbuf[1], xa.x);
        step(hbuf[1], hbuf[0], xa.y);
        step(hbuf[0], hbuf[1], xa.z);
        step(hbuf[1], hbuf[0], xa.w);
        step(hbuf[0], hbuf[1], xc.x);
        step(hbuf[1], hbuf[0], xc.y);
        step(hbuf[0], hbuf[1], xc.z);
        step(hbuf[1], hbuf[0], xc.w);
        xa = xa_n;
        xc = xc_n;
    }

    // Head: h_T in hbuf[0] (TT % 8 == 0). out[b,p] = b_out[p] + W_out[p,:].h_T
    if (tid < PP) {
        const float* wo = W_out + tid * HH;
        float s0 = 0.f, s1 = 0.f, s2 = 0.f, s3 = 0.f;
        #pragma unroll
        for (int h = 0; h < HH; h += 4) {
            s0 = fmaf(wo[h + 0], (float)hbuf[0][h + 0], s0);
            s1 = fmaf(wo[h + 1], (float)hbuf[0][h + 1], s1);
            s2 = fmaf(wo[h + 2], (float)hbuf[0][h + 2], s2);
            s3 = fmaf(wo[h + 3], (float)hbuf[0][h + 3], s3);
        }
        out[b * PP + tid] = b_out[tid] + (s0 + s1) + (s2 + s3);
    }
}

extern "C" void kernel_launch(void* const* d_in, const int* in_sizes, int n_in,
                              void* d_out, int out_size, void* d_ws, size_t ws_size,
                              hipStream_t stream) {
    const float* x     = (const float*)d_in[0];
    const float* W_ih  = (const float*)d_in[1];
    const float* W_hh  = (const float*)d_in[2];
    const float* b_ih  = (const float*)d_in[3];
    const float* b_hh  = (const float*)d_in[4];
    const float* W_out = (const float*)d_in[5];
    const float* b_out = (const float*)d_in[6];
    float* out = (float*)d_out;

    rnn_persist<<<BB, 512, 0, stream>>>(x, W_ih, W_hh, b_ih, b_hh, W_out, b_out, out);
}